// Round 10
// baseline (115.308 us; speedup 1.0000x reference)
//
#include <hip/hip_runtime.h>
#include <hip/hip_bf16.h>

// flex_conv via MFMA + WAVE-PRIVATE async LDS staging, ZERO barriers (v10).
//
// Math (unchanged, validated): t[k=ic*4+d][pixel]: t_d = ctr_d*Xs - PX_d
// (d<3), t_3 = Xs; out[o][pixel] = Kmat[o][k] . t[k][pixel] -> 16x16x32 bf16
// MFMA (A[m=p][k], B[k][n=p], D row=c*4+r col=p).
//
// 9-round plateau: ~42+-5 us kernel across staging style / residency /
// pipeline depth / epilogue / VALU volume, VALUBusy ~20-29%, occ ~25%.
// Last untested axis-cell: async DMA x NO synchronization.  Every fast
// variant still convoyed its 4 waves through __syncthreads (all wait for
// the block's slowest DMA, compute in lockstep).  v10: each wave stages its
// OWN 19-plane x 6-row x 20-col LDS strip (9.1 KB) via global_load_lds,
// drains only its own vmcnt (inline asm, no s_barrier), computes its 16
// output cols.  Waves desync and self-pipeline.  Cost: +18% staged bytes
// (no cross-wave halo sharing), LDS 36.5 KB -> 4 blocks/CU (16 waves).
//
// Alignment/edges: wave col-base wcb=j0+w*16 is 16B-aligned; 18 needed cols
// -> 5 aligned float4 chunks (20 cols).  Only the last wave of the last
// col-block clamps its 5th chunk; the affected cells feed output cols >=510
// which are never stored (j<WP guard; MFMA is column-separable in B).
// LDS read conflicts: x-planes 2-way across c-groups (free, m136); pts
// reads broadcast (same addr for all c).

#define HH 64
#define WW 512
#define HP 62
#define WP 510
#define IC 16
#define OC 32
#define BS 16
#define RB 4            // output rows per block
#define TR (RB + 2)     // staged input rows = 6
#define TC 64           // output cols per block (16 per wave)
#define NPL 19          // planes staged: 16 x + 3 pts
#define WPL 20          // floats per plane-row per wave (need 18; 20 = 5 chunks)
#define WCH 5           // float4 chunks per plane-row per wave
#define WROWS (NPL * TR)        // 114
#define WCHUNK (WROWS * WCH)    // 570 chunks per wave
#define WSLOT (WROWS * WPL)     // 2280 floats per wave slot

typedef __attribute__((ext_vector_type(8))) short short8;
typedef __attribute__((ext_vector_type(4))) float f32x4;

static __device__ __forceinline__ short f2bf(float f) {
    union { __hip_bfloat16 h; short s; } u;
    u.h = __float2bfloat16(f);
    return u.s;
}

__global__ __launch_bounds__(256) void flex_conv_v10(
    const float* __restrict__ x, const float* __restrict__ kern,
    const float* __restrict__ pts, float* __restrict__ out)
{
    __shared__ float lds[4 * WSLOT];   // 9120 floats = 36480 B -> 4 blocks/CU

    const int tid = threadIdx.x;
    const int lane = tid & 63;
    const int wave = tid >> 6;
    const int p = lane & 15;
    const int c = lane >> 4;

    const int j0 = blockIdx.x * TC;
    int i0 = blockIdx.y * RB;
    if (i0 > HP - RB) i0 = HP - RB;        // tail overlap (benign identical rewrite)
    const int b = blockIdx.z;
    const int wcb = j0 + wave * 16;        // this wave's col base (16B-aligned)

    const float* xb = x + (size_t)b * IC * HH * WW;
    const float* pb = pts + (size_t)b * 3 * HH * WW;
    float* const wl = lds + wave * WSLOT;  // this wave's private strip

    // ---- wave-private async staging: 570 16B chunks over 64 lanes ----
    // LDS byte offset of chunk cid is cid*16 from wl -> per round the dest is
    // wave-uniform base (wl + rnd*1024B) + lane*16: the required DMA pattern.
    #pragma unroll
    for (int rnd = 0; rnd < 9; ++rnd) {
        const int cid = lane + rnd * 64;
        if (cid < WCHUNK) {
            const int row = cid / WCH;           // 0..113 = plane*TR + rr
            const int chunk = cid - row * WCH;   // 0..4
            const int plane = row / TR;          // 0..18
            const int rr = row - plane * TR;     // 0..5
            const float* base = (plane < IC)
                ? (xb + (size_t)plane * HH * WW)
                : (pb + (size_t)(plane - IC) * HH * WW);
            int gcol = wcb + chunk * 4;
            if (gcol > WW - 4) gcol = WW - 4;    // clamp (cells only feed j>=WP)
            const float* src = base + (size_t)(i0 + rr) * WW + gcol;
            __builtin_amdgcn_global_load_lds(
                (const __attribute__((address_space(1))) void*)src,
                (__attribute__((address_space(3))) void*)(wl + cid * 4),
                16, 0, 0);
        }
    }

    // ---- A fragments: loaded while this wave's DMA is in flight ----
    short8 a0lo, a0hi, a1lo, a1hi;
    {
        const float4* k0v = (const float4*)(kern + (size_t)p * 64 + c * 8);
        const float4* k1v = (const float4*)(kern + (size_t)(16 + p) * 64 + c * 8);
        float4 v0a = k0v[0], v0b = k0v[1], v0c = k0v[8], v0d = k0v[9];
        float4 v1a = k1v[0], v1b = k1v[1], v1c = k1v[8], v1d = k1v[9];
        a0lo[0]=f2bf(v0a.x); a0lo[1]=f2bf(v0a.y); a0lo[2]=f2bf(v0a.z); a0lo[3]=f2bf(v0a.w);
        a0lo[4]=f2bf(v0b.x); a0lo[5]=f2bf(v0b.y); a0lo[6]=f2bf(v0b.z); a0lo[7]=f2bf(v0b.w);
        a0hi[0]=f2bf(v0c.x); a0hi[1]=f2bf(v0c.y); a0hi[2]=f2bf(v0c.z); a0hi[3]=f2bf(v0c.w);
        a0hi[4]=f2bf(v0d.x); a0hi[5]=f2bf(v0d.y); a0hi[6]=f2bf(v0d.z); a0hi[7]=f2bf(v0d.w);
        a1lo[0]=f2bf(v1a.x); a1lo[1]=f2bf(v1a.y); a1lo[2]=f2bf(v1a.z); a1lo[3]=f2bf(v1a.w);
        a1lo[4]=f2bf(v1b.x); a1lo[5]=f2bf(v1b.y); a1lo[6]=f2bf(v1b.z); a1lo[7]=f2bf(v1b.w);
        a1hi[0]=f2bf(v1c.x); a1hi[1]=f2bf(v1c.y); a1hi[2]=f2bf(v1c.z); a1hi[3]=f2bf(v1c.w);
        a1hi[4]=f2bf(v1d.x); a1hi[5]=f2bf(v1d.y); a1hi[6]=f2bf(v1d.z); a1hi[7]=f2bf(v1d.w);
    }

    // ---- drain ONLY this wave's DMAs (no barrier: strip is wave-private) ----
    asm volatile("s_waitcnt vmcnt(0)" ::: "memory");
    __builtin_amdgcn_sched_barrier(0);   // rule #18: pin dependent ops after wait

    // ---- window partials from the private strip ----
    float xs[4][RB], px0[4][RB], px1[4][RB], px2[4][RB];
    #pragma unroll
    for (int t = 0; t < 4; ++t)
        #pragma unroll
        for (int q = 0; q < RB; ++q) { xs[t][q]=0.f; px0[t][q]=0.f; px1[t][q]=0.f; px2[t][q]=0.f; }
    float c0[RB], c1[RB], c2[RB];

    #pragma unroll
    for (int rr = 0; rr < TR; ++rr) {
        const float* lp0 = wl + ((IC + 0) * TR + rr) * WPL + p;   // pts plane 0
        const float* lp1 = wl + ((IC + 1) * TR + rr) * WPL + p;
        const float* lp2 = wl + ((IC + 2) * TR + rr) * WPL + p;
        const float pa0 = lp0[0], pm0 = lp0[1], pz0 = lp0[2];
        const float pa1 = lp1[0], pm1 = lp1[1], pz1 = lp1[2];
        const float pa2 = lp2[0], pm2 = lp2[1], pz2 = lp2[2];
        if (rr >= 1 && rr <= RB) { c0[rr-1] = pm0; c1[rr-1] = pm1; c2[rr-1] = pm2; }
        #pragma unroll
        for (int t = 0; t < 4; ++t) {
            const int ic = (t >> 1) * 8 + 2 * c + (t & 1);
            const float* lx = wl + (ic * TR + rr) * WPL + p;
            const float x0 = lx[0], x1 = lx[1], x2 = lx[2];
            const float rsx = x0 + x1 + x2;
            float r0 = pa0 * x0; r0 = fmaf(pm0, x1, r0); r0 = fmaf(pz0, x2, r0);
            float r1 = pa1 * x0; r1 = fmaf(pm1, x1, r1); r1 = fmaf(pz1, x2, r1);
            float r2 = pa2 * x0; r2 = fmaf(pm2, x1, r2); r2 = fmaf(pz2, x2, r2);
            #pragma unroll
            for (int q = 0; q < RB; ++q) {
                if (rr >= q && rr <= q + 2) {
                    xs[t][q] += rsx; px0[t][q] += r0; px1[t][q] += r1; px2[t][q] += r2;
                }
            }
        }
    }

    // ---- per output row: B fragments -> MFMA -> store ----
    const int j = wcb + p;
    #pragma unroll
    for (int q = 0; q < RB; ++q) {
        short8 blo, bhi;
        #pragma unroll
        for (int t = 0; t < 4; ++t) {
            const short t0 = f2bf(fmaf(c0[q], xs[t][q], -px0[t][q]));
            const short t1 = f2bf(fmaf(c1[q], xs[t][q], -px1[t][q]));
            const short t2 = f2bf(fmaf(c2[q], xs[t][q], -px2[t][q]));
            const short t3 = f2bf(xs[t][q]);
            const int s = (t & 1) * 4;
            if (t < 2) { blo[s+0]=t0; blo[s+1]=t1; blo[s+2]=t2; blo[s+3]=t3; }
            else       { bhi[s+0]=t0; bhi[s+1]=t1; bhi[s+2]=t2; bhi[s+3]=t3; }
        }
        f32x4 acc0 = {0.f,0.f,0.f,0.f}, acc1 = {0.f,0.f,0.f,0.f};
        acc0 = __builtin_amdgcn_mfma_f32_16x16x32_bf16(a0lo, blo, acc0, 0, 0, 0);
        acc0 = __builtin_amdgcn_mfma_f32_16x16x32_bf16(a0hi, bhi, acc0, 0, 0, 0);
        acc1 = __builtin_amdgcn_mfma_f32_16x16x32_bf16(a1lo, blo, acc1, 0, 0, 0);
        acc1 = __builtin_amdgcn_mfma_f32_16x16x32_bf16(a1hi, bhi, acc1, 0, 0, 0);
        if (j < WP) {
            float* ob = out + (size_t)b * OC * HP * WP + (size_t)(i0 + q) * WP + j;
            #pragma unroll
            for (int r = 0; r < 4; ++r) {
                const int o = c * 4 + r;
                ob[(size_t)o * HP * WP]        = acc0[r];
                ob[(size_t)(o + 16) * HP * WP] = acc1[r];
            }
        }
    }
}

extern "C" void kernel_launch(void* const* d_in, const int* in_sizes, int n_in,
                              void* d_out, int out_size, void* d_ws, size_t ws_size,
                              hipStream_t stream)
{
    const float* x    = (const float*)d_in[0];
    const float* kern = (const float*)d_in[1];
    const float* pts  = (const float*)d_in[2];
    float* out = (float*)d_out;

    dim3 block(256, 1, 1);
    dim3 grid(WW / TC, (HP + RB - 1) / RB, BS);   // 8 x 16 x 16 = 2048 blocks
    flex_conv_v10<<<grid, block, 0, stream>>>(x, kern, pts, out);
}